// Round 3
// baseline (25.302 us; speedup 1.0000x reference)
//
#include <hip/hip_runtime.h>
#include <hip/hip_bf16.h>

// B=64, C=512, Q=64, D=512, fp32 in/out.
// out[b,c,q] = sum_d H[b,c,d] * U'[b,q,d] + s_u[b,q]
//   U'[q,d] = w_hu[d]*U[q,d] + w_h[d]   (folds s_h into the GEMM)
//   s_u[q]  = sum_d w_u[d]*U[q,d]
// Kernel 1 (prep): U -> U' (bf16, fragment-ordered) + s_u, into d_ws.
// Kernel 2 (gemm): barrier-free, LDS-free; H streamed global->reg->cvt,
//                  U' fragments read straight from L2 (coalesced).
//
// ws layout (bytes):
//   [0, 4 MB)        : U' bf16, elem(b,d,q) at b*32768 + (d>>5)*2048
//                      + ((d>>3)&3)*512 + q*8 + (d&7)
//   [4 MB, 4 MB+16K) : s_u fp32 [b][q]

#define Bn 64
#define Cn 512
#define Qn 64
#define Dn 512
#define WS_SU_OFF (4u * 1024u * 1024u)

typedef __bf16 bf16x8 __attribute__((ext_vector_type(8)));
typedef float  f32x4  __attribute__((ext_vector_type(4)));

// ---------------------------------------------------------------- prep ----
__global__ __launch_bounds__(256)
void prep_kernel(const float* __restrict__ U, const float* __restrict__ w,
                 __bf16* __restrict__ wu_out, float* __restrict__ su_out)
{
    const int bid = (int)blockIdx.x;      // 256 blocks
    const int b   = bid >> 2;
    const int qg  = bid & 3;
    const int t   = (int)threadIdx.x;
    const int q   = qg * 16 + (t >> 4);
    const int seg = t & 15;

    const float* __restrict__ Uq = U + ((size_t)(b * Qn + q)) * Dn;
    __bf16* __restrict__ wb = wu_out + (size_t)b * 32768;

    float su = 0.f;
#pragma unroll
    for (int j = 0; j < 4; ++j) {
        const int d0 = seg * 32 + j * 8;
        f32x4 u0  = *(const f32x4*)(Uq + d0);
        f32x4 u1  = *(const f32x4*)(Uq + d0 + 4);
        f32x4 wh0 = *(const f32x4*)(w + d0);
        f32x4 wh1 = *(const f32x4*)(w + d0 + 4);
        f32x4 wu0 = *(const f32x4*)(w + 512 + d0);
        f32x4 wu1 = *(const f32x4*)(w + 512 + d0 + 4);
        f32x4 wm0 = *(const f32x4*)(w + 1024 + d0);
        f32x4 wm1 = *(const f32x4*)(w + 1024 + d0 + 4);
        bf16x8 v;
#pragma unroll
        for (int i = 0; i < 4; ++i) {
            su += wu0[i] * u0[i] + wu1[i] * u1[i];
            v[i]     = (__bf16)__builtin_fmaf(wm0[i], u0[i], wh0[i]);
            v[i + 4] = (__bf16)__builtin_fmaf(wm1[i], u1[i], wh1[i]);
        }
        // d0 = seg*32 + j*8  ->  kt = seg, hh = j
        *(bf16x8*)(wb + seg * 2048 + j * 512 + q * 8) = v;
    }
    su += __shfl_xor(su, 1);
    su += __shfl_xor(su, 2);
    su += __shfl_xor(su, 4);
    su += __shfl_xor(su, 8);
    if (seg == 0) su_out[b * Qn + q] = su;
}

// ---------------------------------------------------------------- gemm ----
__global__ __launch_bounds__(64)
void gemm_kernel(const float* __restrict__ H, const __bf16* __restrict__ Uw,
                 const float* __restrict__ suw, float* __restrict__ out)
{
    // XCD swizzle: XCD x (= bid%8) owns batches 8x..8x+7, all 32 c-blocks,
    // so U'[b] (64 KB) stays resident in that XCD's L2.
    const int r  = (int)blockIdx.x;          // 2048 single-wave blocks
    const int b  = (r & 7) * 8 + ((r >> 3) & 7);
    const int cb = r >> 6;                   // 0..31

    const int lane = (int)threadIdx.x;
    const int ql   = lane & 15;
    const int hh   = lane >> 4;

    const float*  __restrict__ hp = H  + ((size_t)(b * Cn + cb * 16 + ql)) * Dn + hh * 8;
    const __bf16* __restrict__ up = Uw + (size_t)b * 32768 + hh * 512 + ql * 8;

    // ring-4 prefetch on BOTH streams (lead 3) so the FIFO vmcnt discipline
    // never collapses the H pipeline when a U' load is consumed.
    f32x4  ha[4], hb[4];
    bf16x8 uf[4][4];

#pragma unroll
    for (int p = 0; p < 3; ++p) {
        ha[p] = *(const f32x4*)(hp + 32 * p);
        hb[p] = *(const f32x4*)(hp + 32 * p + 4);
#pragma unroll
        for (int n = 0; n < 4; ++n)
            uf[p][n] = *(const bf16x8*)(up + p * 2048 + n * 128);
    }

    f32x4 acc[4] = {{0.f,0.f,0.f,0.f},{0.f,0.f,0.f,0.f},
                    {0.f,0.f,0.f,0.f},{0.f,0.f,0.f,0.f}};

#pragma unroll
    for (int k = 0; k < 16; ++k) {           // fully unrolled, static regs
        if (k + 3 < 16) {
            ha[(k + 3) & 3] = *(const f32x4*)(hp + 32 * (k + 3));
            hb[(k + 3) & 3] = *(const f32x4*)(hp + 32 * (k + 3) + 4);
#pragma unroll
            for (int n = 0; n < 4; ++n)
                uf[(k + 3) & 3][n] = *(const bf16x8*)(up + (k + 3) * 2048 + n * 128);
        }
        f32x4 ca = ha[k & 3], cb2 = hb[k & 3];
        bf16x8 a;
#pragma unroll
        for (int i = 0; i < 4; ++i) {
            a[i]     = (__bf16)ca[i];
            a[i + 4] = (__bf16)cb2[i];
        }
#pragma unroll
        for (int n = 0; n < 4; ++n)
            acc[n] = __builtin_amdgcn_mfma_f32_16x16x32_bf16(a, uf[k & 3][n], acc[n], 0, 0, 0);
    }

    // epilogue: out[c,q] = acc + s_u[q]
    const float* __restrict__ sup  = suw + b * Qn;
    float*       __restrict__ outb = out + ((size_t)(b * Cn + cb * 16)) * Qn;
#pragma unroll
    for (int n = 0; n < 4; ++n) {
        const int q = n * 16 + ql;
        const float s = sup[q];
#pragma unroll
        for (int rr = 0; rr < 4; ++rr)
            outb[(size_t)(hh * 4 + rr) * Qn + q] = acc[n][rr] + s;
    }
}

extern "C" void kernel_launch(void* const* d_in, const int* in_sizes, int n_in,
                              void* d_out, int out_size, void* d_ws, size_t ws_size,
                              hipStream_t stream) {
    const float* H = (const float*)d_in[0];
    const float* U = (const float*)d_in[1];
    const float* w = (const float*)d_in[2];
    float* out = (float*)d_out;

    __bf16* ws_u  = (__bf16*)d_ws;
    float*  ws_su = (float*)((char*)d_ws + WS_SU_OFF);

    prep_kernel<<<dim3(256), dim3(256), 0, stream>>>(U, w, ws_u, ws_su);
    gemm_kernel<<<dim3(2048), dim3(64), 0, stream>>>(H, ws_u, ws_su, out);
}